// Round 1
// baseline (78.610 us; speedup 1.0000x reference)
//
#include <hip/hip_runtime.h>

#define B 32
#define V 256
#define F 128
#define P 64
#define VT 8   // v-tile per block

#define LOG2E 1.44269504088896340736f

// Grid: B * (V/VT) = 1024 blocks x 256 threads.
// tid = vh*128 + f. Thread (f, vh) produces out[b, v0+2k+vh, f] for k=0..VT/2-1.
// amp[b,f,:] (softmaxed) lives in 64 VGPRs per thread; q2[b,:] lives in 64 SGPRs
// (wave-uniform via readfirstlane). Main loop: 4 VALU + 1 v_exp per element,
// no LDS, no barriers. Stores are f-contiguous (coalesced 256B per wave).
__global__ __launch_bounds__(256) void extraction_kernel(
    const float* __restrict__ q2,      // (B, P)
    const float* __restrict__ logits,  // (B, 1, F, P)
    const float* __restrict__ vol,     // (V, 1)
    const float* __restrict__ filt,    // (1, F)
    const float* __restrict__ sigma_p, // (1,)
    float* __restrict__ out)           // (B, V, F)
{
    const int bid = blockIdx.x;
    const int b   = bid >> 5;            // / (V/VT)
    const int v0  = (bid & 31) * VT;     // % (V/VT) * VT
    const int tid = threadIdx.x;
    const int f   = tid & (F - 1);
    const int vh  = tid >> 7;            // 0 or 1 (wave-uniform)

    // ---- per-thread softmax of logits[b,0,f,:] into registers ----
    float amp[P];
    const float4* lg4 = (const float4*)(logits + (b * F + f) * P);
    float m = -3.0e38f;
    #pragma unroll
    for (int j = 0; j < P / 4; ++j) {
        float4 t = lg4[j];
        amp[4 * j + 0] = t.x;
        amp[4 * j + 1] = t.y;
        amp[4 * j + 2] = t.z;
        amp[4 * j + 3] = t.w;
        m = fmaxf(m, fmaxf(fmaxf(t.x, t.y), fmaxf(t.z, t.w)));
    }
    float sum = 0.f;
    #pragma unroll
    for (int p = 0; p < P; ++p) {
        float e = __builtin_amdgcn_exp2f((amp[p] - m) * LOG2E);
        amp[p] = e;
        sum += e;
    }
    const float rs = 1.0f / sum;
    #pragma unroll
    for (int p = 0; p < P; ++p) amp[p] *= rs;

    // ---- scalar constants ----
    const float sig = sigma_p[0];
    const float inv = 1.0f / (sig + 0.001f);
    // exp(-0.5*(d*inv)^2) = 2^(-(s*d)^2) with s = sqrt(0.5*log2(e))*inv.
    // NOTE: keep the (q - x) subtraction in un-scaled fp32 (exact via Sterbenz
    // for nearby values), scale AFTER the subtract — same precision class as
    // the previously-passing kk*d*d form. Do NOT expand the square.
    const float s = sqrtf(0.5f * LOG2E) * inv;

    // ---- q2[b,:] pinned wave-uniform (SGPRs) ----
    float qs[P];
    #pragma unroll
    for (int p = 0; p < P; ++p)
        qs[p] = __uint_as_float(
            __builtin_amdgcn_readfirstlane(__float_as_uint(q2[b * P + p])));

    const float ff = filt[f];

    // ---- main loop: VT/2 v's per thread, 64 p fully unrolled ----
    #pragma unroll 1
    for (int k = 0; k < VT / 2; ++k) {
        const int v = v0 + 2 * k + vh;
        const float x = vol[v] * ff;     // vol[v] wave-uniform, filt[f] per-thread
        float a0 = 0.f, a1 = 0.f, a2 = 0.f, a3 = 0.f;
        #pragma unroll
        for (int p = 0; p < P; p += 4) {
            float t0 = (qs[p + 0] - x) * s;   // v_sub(sgpr) + v_mul(sgpr)
            float t1 = (qs[p + 1] - x) * s;
            float t2 = (qs[p + 2] - x) * s;
            float t3 = (qs[p + 3] - x) * s;
            a0 += amp[p + 0] * __builtin_amdgcn_exp2f(-(t0 * t0));
            a1 += amp[p + 1] * __builtin_amdgcn_exp2f(-(t1 * t1));
            a2 += amp[p + 2] * __builtin_amdgcn_exp2f(-(t2 * t2));
            a3 += amp[p + 3] * __builtin_amdgcn_exp2f(-(t3 * t3));
        }
        out[(b * V + v) * F + f] = (a0 + a1) + (a2 + a3);   // coalesced in f
    }
}

extern "C" void kernel_launch(void* const* d_in, const int* in_sizes, int n_in,
                              void* d_out, int out_size, void* d_ws, size_t ws_size,
                              hipStream_t stream) {
    const float* q2     = (const float*)d_in[0]; // (32, 64)
    const float* logits = (const float*)d_in[1]; // (32, 1, 128, 64)
    const float* vol    = (const float*)d_in[2]; // (256, 1)
    const float* filt   = (const float*)d_in[3]; // (1, 128)
    const float* sigma  = (const float*)d_in[4]; // scalar
    float* out = (float*)d_out;                  // (32, 256, 128)

    extraction_kernel<<<B * (V / VT), 256, 0, stream>>>(q2, logits, vol, filt, sigma, out);
}